// Round 6
// baseline (3142.897 us; speedup 1.0000x reference)
//
#include <hip/hip_runtime.h>
#include <stdint.h>

#define NSITES 256
#define NHID   64
#define BATCH  8192
#define WPB    4      // waves per block
#define SPW    4      // samples per wave

// ---------------- threefry2x32 (exact JAX semantics) ----------------
__device__ __forceinline__ uint32_t rotl32(uint32_t v, int d) {
  return (v << d) | (v >> (32 - d));
}

__device__ __forceinline__ void tf2x32(uint32_t k0, uint32_t k1,
                                       uint32_t x0, uint32_t x1,
                                       uint32_t& o0, uint32_t& o1) {
  uint32_t ks2 = k0 ^ k1 ^ 0x1BD11BDAu;
  x0 += k0; x1 += k1;
#define TFR4(a,b,c,d) \
  x0 += x1; x1 = rotl32(x1,a); x1 ^= x0; \
  x0 += x1; x1 = rotl32(x1,b); x1 ^= x0; \
  x0 += x1; x1 = rotl32(x1,c); x1 ^= x0; \
  x0 += x1; x1 = rotl32(x1,d); x1 ^= x0;
  TFR4(13,15,26,6)   x0 += k1;  x1 += ks2 + 1u;
  TFR4(17,29,16,24)  x0 += ks2; x1 += k0  + 2u;
  TFR4(13,15,26,6)   x0 += k0;  x1 += k1  + 3u;
  TFR4(17,29,16,24)  x0 += k1;  x1 += ks2 + 4u;
  TFR4(13,15,26,6)   x0 += ks2; x1 += k0  + 5u;
#undef TFR4
  o0 = x0; o1 = x1;
}

__device__ __forceinline__ float gumb_from_bits(uint32_t bits) {
  float f = __uint_as_float((bits >> 9) | 0x3f800000u) - 1.0f;
  float u = (f == 0.0f) ? 1.17549435e-38f : f;
  return -logf(-logf(u));
}

__device__ __forceinline__ uint32_t rbits32(uint32_t k0, uint32_t k1, uint32_t e) {
  uint32_t a, b;
  tf2x32(k0, k1, 0u, e, a, b);
  return a ^ b;
}

// ---------------- gumbel precompute kernel ----------------
__global__ void gumbel_precompute(float2* __restrict__ g) {
  int idx = blockIdx.x * blockDim.x + threadIdx.x;
  if (idx >= NSITES * BATCH) return;
  int t = idx >> 13;
  int b = idx & (BATCH - 1);
  uint32_t kt0, kt1;
  tf2x32(0u, 1234u, 0u, (uint32_t)t, kt0, kt1);
  uint32_t r0 = rbits32(kt0, kt1, (uint32_t)(2 * b));
  uint32_t r1 = rbits32(kt0, kt1, (uint32_t)(2 * b + 1));
  g[idx] = make_float2(gumb_from_bits(r0), gumb_from_bits(r1));
}

// XLA's logistic_expander form: 0.5 + 0.5*tanh(0.5*x)
__device__ __forceinline__ float sigmoid_xla(float x) {
  return 0.5f + 0.5f * tanhf(0.5f * x);
}

// ================= LDS-weight kernel: 4 samples per wave ==================
// Wh lives in LDS transposed: col = gate*64 + unit, 64 j-values contiguous,
// stored as float4 chunks with XOR swizzle idx = col*16 + (j4 ^ (col&15))
// so a wave's 64 ds_read_b128 (one column-chunk per lane) are bank-even.
// h is broadcast through a per-wave LDS row hbuf[j] = {hA,hB,hC,hD}: the
// dot loop reads it at a wave-uniform address (free broadcast), eliminating
// per-sample readlane. One weight read feeds 12 fma (3 gates x 4 samples).
// Per-sample arithmetic is bit-identical to the absmax-0.0 round-1 kernel:
// same fmaf chain (j ascending), same sigmoid/tanh/exp/log calls, same
// shuffle-butterfly tree for logits, same selects.

#define GATECOMP(S) \
  const float rz##S = az##S + b1z; \
  const float rr##S = ar##S + b1r; \
  const float rh##S = ah##S + b1h; \
  const float zg##S = sigmoid_xla(xz##S + rz##S); \
  const float rg##S = sigmoid_xla(xr##S + rr##S); \
  const float hg##S = tanhf(xh##S + rg##S * rh##S); \
  h##S = zg##S * h##S + (1.0f - zg##S) * hg##S;

#define LOGITS(S) \
  float p0##S = h##S * wd0, p1##S = h##S * wd1; \
  _Pragma("unroll") \
  for (int off = 32; off > 0; off >>= 1) { \
    p0##S += __shfl_xor(p0##S, off, 64); \
    p1##S += __shfl_xor(p1##S, off, 64); \
  } \
  const float l0##S = p0##S + bd0, l1##S = p1##S + bd1; \
  const float mm##S = fmaxf(l0##S, l1##S); \
  const float sh0##S = l0##S - mm##S, sh1##S = l1##S - mm##S; \
  const float lse##S = logf(expf(sh0##S) + expf(sh1##S));

#define PICK(S, G0, G1) \
  const int s##S = ((l1##S + (G1)) > (l0##S + (G0))) ? 1 : 0; \
  lp##S += (s##S ? sh1##S : sh0##S) - lse##S; \
  xz##S = s##S ? m2z : m1z; \
  xr##S = s##S ? m2r : m1r; \
  xh##S = s##S ? m2h : m1h;

#define DOTJ(HV, WZ, WR, WH) \
  azA = fmaf(HV.x, WZ, azA); azB = fmaf(HV.y, WZ, azB); \
  azC = fmaf(HV.z, WZ, azC); azD = fmaf(HV.w, WZ, azD); \
  arA = fmaf(HV.x, WR, arA); arB = fmaf(HV.y, WR, arB); \
  arC = fmaf(HV.z, WR, arC); arD = fmaf(HV.w, WR, arD); \
  ahA = fmaf(HV.x, WH, ahA); ahB = fmaf(HV.y, WH, ahB); \
  ahC = fmaf(HV.z, WH, ahC); ahD = fmaf(HV.w, WH, ahD);

template <bool PRE>
__global__ __launch_bounds__(256)
void rnn_lds(const float* __restrict__ Wi, const float* __restrict__ Wh,
             const float* __restrict__ bb, const float* __restrict__ Wd,
             const float* __restrict__ bd, const float2* __restrict__ g,
             float* __restrict__ out_s, float* __restrict__ out_lp) {
  __shared__ float4 wlds[192 * 16];   // 48 KiB swizzled transposed Wh
  __shared__ float4 hbuf[WPB][NHID];  // 4 KiB: per-wave h broadcast row

  const int tid  = threadIdx.x;
  const int lane = tid & 63;
  const int wid  = tid >> 6;
  const int base = (blockIdx.x * WPB + wid) * SPW;  // first of 4 samples
  const int l15  = lane & 15;

  // ---- stage Wh -> LDS (transposed + swizzled), cooperative, one-time ----
#pragma unroll
  for (int k = 0; k < 12; ++k) {
    const int flat = tid * 12 + k;        // 0..3071
    const int col = flat >> 4;            // 0..191
    const int j4  = flat & 15;            // j-chunk
    float4 w;
    w.x = Wh[(4 * j4 + 0) * 192 + col];
    w.y = Wh[(4 * j4 + 1) * 192 + col];
    w.z = Wh[(4 * j4 + 2) * 192 + col];
    w.w = Wh[(4 * j4 + 3) * 192 + col];
    wlds[(col << 4) + (j4 ^ (col & 15))] = w;
  }
  hbuf[wid][lane] = make_float4(0.0f, 0.0f, 0.0f, 0.0f);  // h0 = 0

  // ---- per-lane tables (lane = hidden unit) ----
  const float b1z = bb[192 + lane];
  const float b1r = bb[192 + 64 + lane];
  const float b1h = bb[192 + 128 + lane];
  const float m0z = bb[lane], m0r = bb[64 + lane], m0h = bb[128 + lane];
  const float m1z = Wi[lane] + m0z, m1r = Wi[64 + lane] + m0r, m1h = Wi[128 + lane] + m0h;
  const float m2z = Wi[192 + lane] + m0z, m2r = Wi[192 + 64 + lane] + m0r,
              m2h = Wi[192 + 128 + lane] + m0h;
  const float wd0 = Wd[lane * 2 + 0], wd1 = Wd[lane * 2 + 1];
  const float bd0 = bd[0], bd1 = bd[1];

  __syncthreads();

  float hA = 0.0f, hB = 0.0f, hC = 0.0f, hD = 0.0f;
  float lpA = 0.0f, lpB = 0.0f, lpC = 0.0f, lpD = 0.0f;
  float xzA = m0z, xrA = m0r, xhA = m0h;   // t=0: zero one-hot input
  float xzB = m0z, xrB = m0r, xhB = m0h;
  float xzC = m0z, xrC = m0r, xhC = m0h;
  float xzD = m0z, xrD = m0r, xhD = m0h;

  const float4* hrow = hbuf[wid];

  for (int t = 0; t < NSITES; ++t) {
    // gumbels for the 4 samples (wave-uniform addresses, L1 broadcast)
    float g0A, g1A, g0B, g1B, g0C, g1C, g0D, g1D;
    if (PRE) {
      const float4 ga = *reinterpret_cast<const float4*>(&g[t * BATCH + base]);
      const float4 gb = *reinterpret_cast<const float4*>(&g[t * BATCH + base + 2]);
      g0A = ga.x; g1A = ga.y; g0B = ga.z; g1B = ga.w;
      g0C = gb.x; g1C = gb.y; g0D = gb.z; g1D = gb.w;
    } else {
      uint32_t kt0, kt1;
      tf2x32(0u, 1234u, 0u, (uint32_t)t, kt0, kt1);
      g0A = gumb_from_bits(rbits32(kt0, kt1, (uint32_t)(2 * (base + 0))));
      g1A = gumb_from_bits(rbits32(kt0, kt1, (uint32_t)(2 * (base + 0) + 1)));
      g0B = gumb_from_bits(rbits32(kt0, kt1, (uint32_t)(2 * (base + 1))));
      g1B = gumb_from_bits(rbits32(kt0, kt1, (uint32_t)(2 * (base + 1) + 1)));
      g0C = gumb_from_bits(rbits32(kt0, kt1, (uint32_t)(2 * (base + 2))));
      g1C = gumb_from_bits(rbits32(kt0, kt1, (uint32_t)(2 * (base + 2) + 1)));
      g0D = gumb_from_bits(rbits32(kt0, kt1, (uint32_t)(2 * (base + 3))));
      g1D = gumb_from_bits(rbits32(kt0, kt1, (uint32_t)(2 * (base + 3) + 1)));
    }

    // ---- mh = h @ Wh for 4 samples (fmaf chain over j ascending) ----
    float azA = 0.0f, azB = 0.0f, azC = 0.0f, azD = 0.0f;
    float arA = 0.0f, arB = 0.0f, arC = 0.0f, arD = 0.0f;
    float ahA = 0.0f, ahB = 0.0f, ahC = 0.0f, ahD = 0.0f;
#pragma unroll
    for (int j4 = 0; j4 < 16; ++j4) {
      const int widx = (lane << 4) + (j4 ^ l15);
      const float4 wz4 = wlds[widx];
      const float4 wr4 = wlds[1024 + widx];
      const float4 wh4 = wlds[2048 + widx];
      const float4 h0 = hrow[4 * j4 + 0];
      const float4 h1 = hrow[4 * j4 + 1];
      const float4 h2 = hrow[4 * j4 + 2];
      const float4 h3 = hrow[4 * j4 + 3];
      DOTJ(h0, wz4.x, wr4.x, wh4.x)
      DOTJ(h1, wz4.y, wr4.y, wh4.y)
      DOTJ(h2, wz4.z, wr4.z, wh4.z)
      DOTJ(h3, wz4.w, wr4.w, wh4.w)
    }

    // ---- gates + h update (bit-identical per sample) ----
    GATECOMP(A) GATECOMP(B) GATECOMP(C) GATECOMP(D)

    // publish new h for next step's dot (wave-coherent, no barrier needed)
    hbuf[wid][lane] = make_float4(hA, hB, hC, hD);

    // ---- logits via the exact shuffle-butterfly tree ----
    LOGITS(A) LOGITS(B) LOGITS(C) LOGITS(D)

    // ---- sample + logp + next-step input select ----
    PICK(A, g0A, g1A) PICK(B, g0B, g1B) PICK(C, g0C, g1C) PICK(D, g0D, g1D)

    if (lane < SPW) {
      const float sv = (lane == 0) ? (float)sA
                     : (lane == 1) ? (float)sB
                     : (lane == 2) ? (float)sC : (float)sD;
      out_s[(size_t)(base + lane) * NSITES + t] = sv;
    }
  }

  if (lane < SPW) {
    const float lv = (lane == 0) ? lpA : (lane == 1) ? lpB
                   : (lane == 2) ? lpC : lpD;
    out_lp[base + lane] = 0.5f * lv;
  }
}

extern "C" void kernel_launch(void* const* d_in, const int* in_sizes, int n_in,
                              void* d_out, int out_size, void* d_ws, size_t ws_size,
                              hipStream_t stream) {
  const float* Wi = (const float*)d_in[1];
  const float* Wh = (const float*)d_in[2];
  const float* bb = (const float*)d_in[3];
  const float* Wd = (const float*)d_in[4];
  const float* bd = (const float*)d_in[5];

  float* out    = (float*)d_out;
  float* out_s  = out;                           // [8192][256]
  float* out_lp = out + (size_t)BATCH * NSITES;  // [8192]

  const int blocks = BATCH / (WPB * SPW);        // 512
  const size_t gbytes = (size_t)NSITES * BATCH * sizeof(float2);
  if (ws_size >= gbytes) {
    float2* g = (float2*)d_ws;
    gumbel_precompute<<<(NSITES * BATCH) / 256, 256, 0, stream>>>(g);
    rnn_lds<true><<<blocks, WPB * 64, 0, stream>>>(Wi, Wh, bb, Wd, bd, g, out_s, out_lp);
  } else {
    rnn_lds<false><<<blocks, WPB * 64, 0, stream>>>(Wi, Wh, bb, Wd, bd, nullptr, out_s, out_lp);
  }
}

// Round 7
// 1463.205 us; speedup vs baseline: 2.1480x; 2.1480x over previous
//
#include <hip/hip_runtime.h>
#include <stdint.h>

#define NSITES 256
#define NHID   64
#define BATCH  8192

typedef float v4f __attribute__((ext_vector_type(4)));

// ---------------- threefry2x32 (exact JAX semantics) ----------------
__device__ __forceinline__ uint32_t rotl32(uint32_t v, int d) {
  return (v << d) | (v >> (32 - d));
}

__device__ __forceinline__ void tf2x32(uint32_t k0, uint32_t k1,
                                       uint32_t x0, uint32_t x1,
                                       uint32_t& o0, uint32_t& o1) {
  uint32_t ks2 = k0 ^ k1 ^ 0x1BD11BDAu;
  x0 += k0; x1 += k1;
#define TFR4(a,b,c,d) \
  x0 += x1; x1 = rotl32(x1,a); x1 ^= x0; \
  x0 += x1; x1 = rotl32(x1,b); x1 ^= x0; \
  x0 += x1; x1 = rotl32(x1,c); x1 ^= x0; \
  x0 += x1; x1 = rotl32(x1,d); x1 ^= x0;
  TFR4(13,15,26,6)   x0 += k1;  x1 += ks2 + 1u;
  TFR4(17,29,16,24)  x0 += ks2; x1 += k0  + 2u;
  TFR4(13,15,26,6)   x0 += k0;  x1 += k1  + 3u;
  TFR4(17,29,16,24)  x0 += k1;  x1 += ks2 + 4u;
  TFR4(13,15,26,6)   x0 += ks2; x1 += k0  + 5u;
#undef TFR4
  o0 = x0; o1 = x1;
}

__device__ __forceinline__ float gumb_from_bits(uint32_t bits) {
  float f = __uint_as_float((bits >> 9) | 0x3f800000u) - 1.0f;
  float u = (f == 0.0f) ? 1.17549435e-38f : f;
  return -logf(-logf(u));
}

__device__ __forceinline__ uint32_t rbits32(uint32_t k0, uint32_t k1, uint32_t e) {
  uint32_t a, b;
  tf2x32(k0, k1, 0u, e, a, b);
  return a ^ b;
}

// ---------------- gumbel precompute kernel ----------------
__global__ void gumbel_precompute(float2* __restrict__ g) {
  int idx = blockIdx.x * blockDim.x + threadIdx.x;
  if (idx >= NSITES * BATCH) return;
  int t = idx >> 13;
  int b = idx & (BATCH - 1);
  uint32_t kt0, kt1;
  tf2x32(0u, 1234u, 0u, (uint32_t)t, kt0, kt1);
  uint32_t r0 = rbits32(kt0, kt1, (uint32_t)(2 * b));
  uint32_t r1 = rbits32(kt0, kt1, (uint32_t)(2 * b + 1));
  g[idx] = make_float2(gumb_from_bits(r0), gumb_from_bits(r1));
}

// ---------------- Wh transpose: WhT[(gate*64+l)*64 + j] = Wh[j*192+gate*64+l]
__global__ void transpose_wh(const float* __restrict__ Wh, float* __restrict__ WhT) {
  int idx = blockIdx.x * 256 + threadIdx.x;   // 0..12287
  if (idx >= 3 * 64 * 64) return;
  int gate = idx >> 12;
  int rem  = idx & 4095;
  int l    = rem >> 6;
  int j    = rem & 63;
  WhT[idx] = Wh[j * 192 + gate * 64 + l];
}

// XLA's logistic_expander form: 0.5 + 0.5*tanh(0.5*x)
__device__ __forceinline__ float sigmoid_xla(float x) {
  return 0.5f + 0.5f * tanhf(0.5f * x);
}

// opaque load: the RA cannot rematerialize an inline-asm result, so the
// 48 dwordx4 weight loads below MUST stay in architectural VGPRs.
#define ASM_LD4(dst, ptr) \
  asm volatile("global_load_dwordx4 %0, %1, off" : "=v"(dst) : "v"(ptr))

// ================= one sample per wave, weights truly VGPR-resident =======
__global__ __launch_bounds__(64) __attribute__((amdgpu_waves_per_eu(2, 2)))
void rnn_asm(const float* __restrict__ Wi, const float* __restrict__ WhT,
             const float* __restrict__ bb, const float* __restrict__ Wd,
             const float* __restrict__ bd, const float2* __restrict__ g,
             float* __restrict__ out_s, float* __restrict__ out_lp) {
  __shared__ float occ_clamp[5120];          // 20 KiB -> max 8 blocks/CU (2 waves/EU)
  const int lane = threadIdx.x;
  const int b = blockIdx.x;
  ((volatile float*)occ_clamp)[lane] = 0.0f;

  // ---- 48 opaque dwordx4 loads: lane's 192 weights, contiguous in WhT ----
  v4f wz4[16], wr4[16], wh4[16];
  const float* pz = WhT + (size_t)lane * 64;
  const float* pr = WhT + (size_t)(64 + lane) * 64;
  const float* ph = WhT + (size_t)(128 + lane) * 64;
#pragma unroll
  for (int j4 = 0; j4 < 16; ++j4) {
    ASM_LD4(wz4[j4], pz + 4 * j4);
    ASM_LD4(wr4[j4], pr + 4 * j4);
    ASM_LD4(wh4[j4], ph + 4 * j4);
  }
  asm volatile("s_waitcnt vmcnt(0)" ::: "memory");
  __builtin_amdgcn_sched_barrier(0);

  const float b1z = bb[192 + lane];
  const float b1r = bb[192 + 64 + lane];
  const float b1h = bb[192 + 128 + lane];
  const float m0z = bb[lane], m0r = bb[64 + lane], m0h = bb[128 + lane];
  float m1z = Wi[lane] + m0z, m1r = Wi[64 + lane] + m0r, m1h = Wi[128 + lane] + m0h;
  float m2z = Wi[192 + lane] + m0z, m2r = Wi[192 + 64 + lane] + m0r,
        m2h = Wi[192 + 128 + lane] + m0h;
  const float wd0 = Wd[lane * 2 + 0], wd1 = Wd[lane * 2 + 1];
  const float bd0 = bd[0], bd1 = bd[1];

  float h = 0.0f, lpsum = 0.0f;
  float xz = m0z, xr = m0r, xh = m0h;   // t=0: zero one-hot input

  for (int t = 0; t < NSITES; ++t) {
    const float2 gc = g[t * BATCH + b];
    const float g0 = gc.x, g1 = gc.y;

    // mh = h @ Wh (identical fmaf chain, j ascending; weights from asm regs)
    float az = 0.0f, ar = 0.0f, ah = 0.0f;
#pragma unroll
    for (int j = 0; j < NHID; ++j) {
      const float hj = __int_as_float(__builtin_amdgcn_readlane(__float_as_int(h), j));
      az = fmaf(hj, wz4[j >> 2][j & 3], az);
      ar = fmaf(hj, wr4[j >> 2][j & 3], ar);
      ah = fmaf(hj, wh4[j >> 2][j & 3], ah);
    }
    const float rz = az + b1z;
    const float rr = ar + b1r;
    const float rh = ah + b1h;

    const float zg = sigmoid_xla(xz + rz);
    const float rg = sigmoid_xla(xr + rr);
    const float hg = tanhf(xh + rg * rh);
    h = zg * h + (1.0f - zg) * hg;

    float p0 = h * wd0, p1 = h * wd1;
#pragma unroll
    for (int off = 32; off > 0; off >>= 1) {
      p0 += __shfl_xor(p0, off, 64);
      p1 += __shfl_xor(p1, off, 64);
    }
    const float l0 = p0 + bd0, l1 = p1 + bd1;

    const float mmax = fmaxf(l0, l1);
    const float sh0 = l0 - mmax, sh1 = l1 - mmax;
    const float lse = logf(expf(sh0) + expf(sh1));

    const int s = ((l1 + g1) > (l0 + g0)) ? 1 : 0;

    lpsum += (s ? sh1 : sh0) - lse;
    if (lane == 0) out_s[(size_t)b * NSITES + t] = (float)s;
    xz = s ? m2z : m1z;
    xr = s ? m2r : m1r;
    xh = s ? m2h : m1h;
  }

  if (lane == 0) out_lp[b] = 0.5f * lpsum;
}

// ---------------- fallback (ws too small): plain bit-exact path ----------
__global__ __launch_bounds__(64)
void rnn_plain(const float* __restrict__ Wi, const float* __restrict__ Wh,
               const float* __restrict__ bb, const float* __restrict__ Wd,
               const float* __restrict__ bd,
               float* __restrict__ out_s, float* __restrict__ out_lp) {
  const int lane = threadIdx.x;
  const int b = blockIdx.x;

  float wz[NHID], wr[NHID], wh[NHID];
#pragma unroll
  for (int j = 0; j < NHID; ++j) {
    wz[j] = Wh[j * 192 + lane];
    wr[j] = Wh[j * 192 + 64 + lane];
    wh[j] = Wh[j * 192 + 128 + lane];
  }
  const float b1z = bb[192 + lane];
  const float b1r = bb[192 + 64 + lane];
  const float b1h = bb[192 + 128 + lane];
  const float m0z = bb[lane], m0r = bb[64 + lane], m0h = bb[128 + lane];
  const float m1z = Wi[lane] + m0z, m1r = Wi[64 + lane] + m0r, m1h = Wi[128 + lane] + m0h;
  const float m2z = Wi[192 + lane] + m0z, m2r = Wi[192 + 64 + lane] + m0r,
              m2h = Wi[192 + 128 + lane] + m0h;
  const float wd0 = Wd[lane * 2 + 0], wd1 = Wd[lane * 2 + 1];
  const float bd0 = bd[0], bd1 = bd[1];

  float h = 0.0f, lpsum = 0.0f;
  float xz = m0z, xr = m0r, xh = m0h;

  for (int t = 0; t < NSITES; ++t) {
    uint32_t kt0, kt1;
    tf2x32(0u, 1234u, 0u, (uint32_t)t, kt0, kt1);
    const float g0 = gumb_from_bits(rbits32(kt0, kt1, (uint32_t)(2 * b)));
    const float g1 = gumb_from_bits(rbits32(kt0, kt1, (uint32_t)(2 * b + 1)));

    float az = 0.0f, ar = 0.0f, ah = 0.0f;
#pragma unroll
    for (int j = 0; j < NHID; ++j) {
      const float hj = __int_as_float(__builtin_amdgcn_readlane(__float_as_int(h), j));
      az = fmaf(hj, wz[j], az);
      ar = fmaf(hj, wr[j], ar);
      ah = fmaf(hj, wh[j], ah);
    }
    const float rz = az + b1z, rr = ar + b1r, rh = ah + b1h;
    const float zg = sigmoid_xla(xz + rz);
    const float rg = sigmoid_xla(xr + rr);
    const float hg = tanhf(xh + rg * rh);
    h = zg * h + (1.0f - zg) * hg;

    float p0 = h * wd0, p1 = h * wd1;
#pragma unroll
    for (int off = 32; off > 0; off >>= 1) {
      p0 += __shfl_xor(p0, off, 64);
      p1 += __shfl_xor(p1, off, 64);
    }
    const float l0 = p0 + bd0, l1 = p1 + bd1;
    const float mmax = fmaxf(l0, l1);
    const float sh0 = l0 - mmax, sh1 = l1 - mmax;
    const float lse = logf(expf(sh0) + expf(sh1));
    const int s = ((l1 + g1) > (l0 + g0)) ? 1 : 0;
    lpsum += (s ? sh1 : sh0) - lse;
    if (lane == 0) out_s[(size_t)b * NSITES + t] = (float)s;
    xz = s ? m2z : m1z;
    xr = s ? m2r : m1r;
    xh = s ? m2h : m1h;
  }

  if (lane == 0) out_lp[b] = 0.5f * lpsum;
}

extern "C" void kernel_launch(void* const* d_in, const int* in_sizes, int n_in,
                              void* d_out, int out_size, void* d_ws, size_t ws_size,
                              hipStream_t stream) {
  const float* Wi = (const float*)d_in[1];
  const float* Wh = (const float*)d_in[2];
  const float* bb = (const float*)d_in[3];
  const float* Wd = (const float*)d_in[4];
  const float* bd = (const float*)d_in[5];

  float* out    = (float*)d_out;
  float* out_s  = out;                           // [8192][256]
  float* out_lp = out + (size_t)BATCH * NSITES;  // [8192]

  const size_t gbytes  = (size_t)NSITES * BATCH * sizeof(float2);  // 16 MiB
  const size_t whbytes = (size_t)3 * 64 * 64 * sizeof(float);      // 48 KiB

  if (ws_size >= gbytes + whbytes) {
    float2* g   = (float2*)d_ws;
    float* WhT  = (float*)((char*)d_ws + gbytes);
    gumbel_precompute<<<(NSITES * BATCH) / 256, 256, 0, stream>>>(g);
    transpose_wh<<<(3 * 64 * 64 + 255) / 256, 256, 0, stream>>>(Wh, WhT);
    rnn_asm<<<BATCH, 64, 0, stream>>>(Wi, WhT, bb, Wd, bd, g, out_s, out_lp);
  } else {
    rnn_plain<<<BATCH, 64, 0, stream>>>(Wi, Wh, bb, Wd, bd, out_s, out_lp);
  }
}